// Round 4
// baseline (495.777 us; speedup 1.0000x reference)
//
#include <hip/hip_runtime.h>

#define MODEL_D 128
#define NO   40            // nodes owned per block (250 * 40 = 10000)
#define NT   1024          // threads per block (16 waves)
#define NW   (NT / 64)     // waves per block
#define NG   (NT / MODEL_D)// 8 column-groups for the MLP phase
#define NPG  (NO / NG)     // 5 nodes per group

// ---------------------------------------------------------------------------
// One kernel does everything. Block b owns nodes [b*NO, b*NO+NO):
//   phase 1: zero LDS agg + load own feat rows into LDS
//   phase 2: scan ALL edges (int4 loads of dst); ballot hits into own range;
//            per hit, wave-cooperatively gather feat[src] row (float2/lane)
//            and accumulate into LDS with ds_add_f32. No global atomics.
//   phase 3: 3-layer MLP on the 40 owned nodes straight out of LDS.
// ---------------------------------------------------------------------------
__global__ __launch_bounds__(NT) void fused_gnn_kernel(
    const float* __restrict__ feat,
    const int* __restrict__ src,
    const int* __restrict__ dst,
    const float* __restrict__ W1, const float* __restrict__ b1,
    const float* __restrict__ W2, const float* __restrict__ b2,
    const float* __restrict__ W3, const float* __restrict__ b3,
    float* __restrict__ out,
    int N, int E)
{
    __shared__ float xs[NO][2 * MODEL_D];  // 40 KB: cols 0..127 agg, 128..255 own feat
    __shared__ float hs[NO][MODEL_D];      // 20 KB: h1

    const int t  = threadIdx.x;
    const int n0 = blockIdx.x * NO;
    const int nNodes = min(NO, N - n0);

    const int j = t & (MODEL_D - 1);   // 0..127
    const int g = t >> 7;              // 0..7

    // ---- phase 1: init LDS ----
    #pragma unroll
    for (int u = 0; u < NPG; ++u) {
        int nl = g * NPG + u;
        int node = n0 + nl;
        xs[nl][j] = 0.f;
        xs[nl][MODEL_D + j] = (node < N) ? feat[(size_t)node * MODEL_D + j] : 0.f;
    }
    __syncthreads();

    // ---- phase 2: edge scan + LDS accumulation ----
    const int wid  = t >> 6;
    const int lane = t & 63;
    for (int base = wid * 256; base < E; base += NW * 256) {
        int e0 = base + lane * 4;
        int4 dv;
        if (e0 + 3 < E) {
            dv = *reinterpret_cast<const int4*>(dst + e0);
        } else {
            dv.x = (e0 + 0 < E) ? dst[e0 + 0] : -1;
            dv.y = (e0 + 1 < E) ? dst[e0 + 1] : -1;
            dv.z = (e0 + 2 < E) ? dst[e0 + 2] : -1;
            dv.w = (e0 + 3 < E) ? dst[e0 + 3] : -1;
        }
        #pragma unroll
        for (int c = 0; c < 4; ++c) {
            int d = (&dv.x)[c];
            unsigned long long mask = __ballot((unsigned)(d - n0) < (unsigned)nNodes);
            while (mask) {
                int b = __ffsll(mask) - 1;
                mask &= mask - 1;
                int e  = base + b * 4 + c;        // wave-uniform
                int dd = __shfl(d, b);            // hit's dst (uniform)
                int s  = src[e];                  // uniform address -> broadcast
                float2 f = *reinterpret_cast<const float2*>(
                    feat + (size_t)s * MODEL_D + lane * 2);
                atomicAdd(&xs[dd - n0][lane * 2 + 0], f.x);  // ds_add_f32
                atomicAdd(&xs[dd - n0][lane * 2 + 1], f.y);
            }
        }
    }
    __syncthreads();

    // ---- phase 3: MLP on owned nodes ----
    float acc[NPG];

    // layer 1: [2D] -> [D], ReLU   (x = xs row = [agg | feat], matches concat)
    {
        float bias = b1[j];
        #pragma unroll
        for (int u = 0; u < NPG; ++u) acc[u] = bias;
        for (int k = 0; k < 2 * MODEL_D; k += 4) {
            float w0 = W1[(k + 0) * MODEL_D + j];
            float w1 = W1[(k + 1) * MODEL_D + j];
            float w2 = W1[(k + 2) * MODEL_D + j];
            float w3 = W1[(k + 3) * MODEL_D + j];
            #pragma unroll
            for (int u = 0; u < NPG; ++u) {
                float4 x = *reinterpret_cast<const float4*>(&xs[g * NPG + u][k]);
                acc[u] = fmaf(x.x, w0, acc[u]);
                acc[u] = fmaf(x.y, w1, acc[u]);
                acc[u] = fmaf(x.z, w2, acc[u]);
                acc[u] = fmaf(x.w, w3, acc[u]);
            }
        }
        #pragma unroll
        for (int u = 0; u < NPG; ++u) hs[g * NPG + u][j] = fmaxf(acc[u], 0.f);
    }
    __syncthreads();

    // layer 2: [D] -> [D], ReLU  (h2 written into xs cols 0..127)
    {
        float bias = b2[j];
        #pragma unroll
        for (int u = 0; u < NPG; ++u) acc[u] = bias;
        for (int k = 0; k < MODEL_D; k += 4) {
            float w0 = W2[(k + 0) * MODEL_D + j];
            float w1 = W2[(k + 1) * MODEL_D + j];
            float w2 = W2[(k + 2) * MODEL_D + j];
            float w3 = W2[(k + 3) * MODEL_D + j];
            #pragma unroll
            for (int u = 0; u < NPG; ++u) {
                float4 x = *reinterpret_cast<const float4*>(&hs[g * NPG + u][k]);
                acc[u] = fmaf(x.x, w0, acc[u]);
                acc[u] = fmaf(x.y, w1, acc[u]);
                acc[u] = fmaf(x.z, w2, acc[u]);
                acc[u] = fmaf(x.w, w3, acc[u]);
            }
        }
        #pragma unroll
        for (int u = 0; u < NPG; ++u) xs[g * NPG + u][j] = fmaxf(acc[u], 0.f);
    }
    __syncthreads();

    // layer 3: [D] -> [D]
    {
        float bias = b3[j];
        #pragma unroll
        for (int u = 0; u < NPG; ++u) acc[u] = bias;
        for (int k = 0; k < MODEL_D; k += 4) {
            float w0 = W3[(k + 0) * MODEL_D + j];
            float w1 = W3[(k + 1) * MODEL_D + j];
            float w2 = W3[(k + 2) * MODEL_D + j];
            float w3 = W3[(k + 3) * MODEL_D + j];
            #pragma unroll
            for (int u = 0; u < NPG; ++u) {
                float4 x = *reinterpret_cast<const float4*>(&xs[g * NPG + u][k]);
                acc[u] = fmaf(x.x, w0, acc[u]);
                acc[u] = fmaf(x.y, w1, acc[u]);
                acc[u] = fmaf(x.z, w2, acc[u]);
                acc[u] = fmaf(x.w, w3, acc[u]);
            }
        }
        #pragma unroll
        for (int u = 0; u < NPG; ++u) {
            int node = n0 + g * NPG + u;
            if (node < N) out[(size_t)node * MODEL_D + j] = acc[u];
        }
    }
}

extern "C" void kernel_launch(void* const* d_in, const int* in_sizes, int n_in,
                              void* d_out, int out_size, void* d_ws, size_t ws_size,
                              hipStream_t stream) {
    const float* feat = (const float*)d_in[0];
    const int*   src  = (const int*)d_in[1];
    const int*   dst  = (const int*)d_in[2];
    const float* W1   = (const float*)d_in[3];
    const float* b1   = (const float*)d_in[4];
    const float* W2   = (const float*)d_in[5];
    const float* b2   = (const float*)d_in[6];
    const float* W3   = (const float*)d_in[7];
    const float* b3   = (const float*)d_in[8];
    float* out = (float*)d_out;

    const int N = in_sizes[0] / MODEL_D;
    const int E = in_sizes[1];

    int NB = (N + NO - 1) / NO;   // 250 blocks, ~1 per CU
    fused_gnn_kernel<<<NB, NT, 0, stream>>>(
        feat, src, dst, W1, b1, W2, b2, W3, b3, out, N, E);
}

// Round 5
// 308.445 us; speedup vs baseline: 1.6073x; 1.6073x over previous
//
#include <hip/hip_runtime.h>

#define MODEL_D 128
#define NPB 16      // nodes per block in MLP kernel
#define MLP_THREADS 256
#define K_SUB 8     // sub-cursors per node (contention reduction)

// ---------------------------------------------------------------------------
// Step 1: histogram of dst -> deg8[] (8 sub-counters per node, keyed by i&7)
// ---------------------------------------------------------------------------
__global__ __launch_bounds__(1024) void hist_kernel(
    const int* __restrict__ dst, int* __restrict__ deg8, int E)
{
    int i = blockIdx.x * 1024 + threadIdx.x;
    int stride = gridDim.x * 1024;
    for (; i < E; i += stride)
        atomicAdd(&deg8[dst[i] * K_SUB + (i & (K_SUB - 1))], 1);
}

// ---------------------------------------------------------------------------
// Step 2: exclusive scan of deg8[8N] -> off8, cursor8 (single block, 1024 thr)
// In-order scan => the 8 sublists of each node are contiguous in srcSorted.
// ---------------------------------------------------------------------------
__global__ __launch_bounds__(1024) void scan_kernel(
    const int* __restrict__ deg8, int* __restrict__ off8,
    int* __restrict__ cursor8, int M /* = 8N */)
{
    __shared__ int sums[1024];
    int t = threadIdx.x;
    int chunk = (M + 1023) >> 10;
    int start = t * chunk;
    int end = min(start + chunk, M);
    int s = 0;
    for (int i = start; i < end; ++i) s += deg8[i];
    sums[t] = s;
    __syncthreads();
    for (int d = 1; d < 1024; d <<= 1) {
        int v = (t >= d) ? sums[t - d] : 0;
        __syncthreads();
        sums[t] += v;
        __syncthreads();
    }
    int pre = (t == 0) ? 0 : sums[t - 1];
    for (int i = start; i < end; ++i) {
        off8[i] = pre;
        cursor8[i] = pre;
        pre += deg8[i];
    }
}

// ---------------------------------------------------------------------------
// Step 3: bucket fill -> srcSorted[] grouped by dst (8-way sub-cursors:
// contention per atomic address drops 64 -> 8)
// ---------------------------------------------------------------------------
__global__ __launch_bounds__(1024) void fill_kernel(
    const int* __restrict__ src, const int* __restrict__ dst,
    int* __restrict__ cursor8, int* __restrict__ srcSorted, int E)
{
    int i = blockIdx.x * 1024 + threadIdx.x;
    int stride = gridDim.x * 1024;
    for (; i < E; i += stride) {
        int pos = atomicAdd(&cursor8[dst[i] * K_SUB + (i & (K_SUB - 1))], 1);
        srcSorted[pos] = src[i];
    }
}

// ---------------------------------------------------------------------------
// Step 4: CSR aggregation, one thread per (node, column). Node's edges are
// the contiguous union of its 8 sublists: [off8[n*8], off8[n*8+7]+deg8[n*8+7]).
// 5000 blocks x 256 threads = full occupancy; unroll-8 gathers.
// ---------------------------------------------------------------------------
__global__ __launch_bounds__(256) void agg_kernel(
    const float* __restrict__ feat,
    const int* __restrict__ off8, const int* __restrict__ deg8,
    const int* __restrict__ srcSorted,
    float* __restrict__ agg, int N)
{
    int gid = blockIdx.x * 256 + threadIdx.x;
    int node = gid >> 7;
    if (node >= N) return;
    int j = gid & (MODEL_D - 1);

    int base8 = node * K_SUB;
    int beg = off8[base8];
    int cnt = off8[base8 + K_SUB - 1] + deg8[base8 + K_SUB - 1] - beg;

    float a = 0.f;
    int i = 0;
    for (; i + 8 <= cnt; i += 8) {
        int s0 = srcSorted[beg + i + 0];
        int s1 = srcSorted[beg + i + 1];
        int s2 = srcSorted[beg + i + 2];
        int s3 = srcSorted[beg + i + 3];
        int s4 = srcSorted[beg + i + 4];
        int s5 = srcSorted[beg + i + 5];
        int s6 = srcSorted[beg + i + 6];
        int s7 = srcSorted[beg + i + 7];
        float f0 = feat[(size_t)s0 * MODEL_D + j];
        float f1 = feat[(size_t)s1 * MODEL_D + j];
        float f2 = feat[(size_t)s2 * MODEL_D + j];
        float f3 = feat[(size_t)s3 * MODEL_D + j];
        float f4 = feat[(size_t)s4 * MODEL_D + j];
        float f5 = feat[(size_t)s5 * MODEL_D + j];
        float f6 = feat[(size_t)s6 * MODEL_D + j];
        float f7 = feat[(size_t)s7 * MODEL_D + j];
        a += ((f0 + f1) + (f2 + f3)) + ((f4 + f5) + (f6 + f7));
    }
    for (; i < cnt; ++i)
        a += feat[(size_t)srcSorted[beg + i] * MODEL_D + j];
    agg[(size_t)node * MODEL_D + j] = a;
}

// ---------------------------------------------------------------------------
// Step 5: 3-layer MLP. 256 threads/block, 16 nodes/block (625 blocks).
// ---------------------------------------------------------------------------
__global__ __launch_bounds__(MLP_THREADS) void mlp_kernel(
    const float* __restrict__ agg,
    const float* __restrict__ feat,
    const float* __restrict__ W1, const float* __restrict__ b1,
    const float* __restrict__ W2, const float* __restrict__ b2,
    const float* __restrict__ W3, const float* __restrict__ b3,
    float* __restrict__ out,
    int N)
{
    __shared__ float xs[NPB][2 * MODEL_D];  // 16 KB
    __shared__ float hs[NPB][MODEL_D];      // 8 KB

    const int t = threadIdx.x;
    const int j = t & (MODEL_D - 1);
    const int g = t >> 7;          // 0..1
    const int n0 = blockIdx.x * NPB;

    #pragma unroll
    for (int u = 0; u < NPB / 2; ++u) {
        int n = g * (NPB / 2) + u;
        int node = n0 + n;
        float a = 0.f, f = 0.f;
        if (node < N) {
            a = agg[(size_t)node * MODEL_D + j];
            f = feat[(size_t)node * MODEL_D + j];
        }
        xs[n][j] = a;
        xs[n][MODEL_D + j] = f;
    }
    __syncthreads();

    const int nbase = g * (NPB / 2);
    float acc[NPB / 2];

    // ---- layer 1: [2D] -> [D], ReLU ----
    {
        float bias = b1[j];
        #pragma unroll
        for (int n = 0; n < NPB / 2; ++n) acc[n] = bias;
        for (int k = 0; k < 2 * MODEL_D; k += 4) {
            float w0 = W1[(k + 0) * MODEL_D + j];
            float w1 = W1[(k + 1) * MODEL_D + j];
            float w2 = W1[(k + 2) * MODEL_D + j];
            float w3 = W1[(k + 3) * MODEL_D + j];
            #pragma unroll
            for (int n = 0; n < NPB / 2; ++n) {
                float4 x = *reinterpret_cast<const float4*>(&xs[nbase + n][k]);
                acc[n] = fmaf(x.x, w0, acc[n]);
                acc[n] = fmaf(x.y, w1, acc[n]);
                acc[n] = fmaf(x.z, w2, acc[n]);
                acc[n] = fmaf(x.w, w3, acc[n]);
            }
        }
        #pragma unroll
        for (int n = 0; n < NPB / 2; ++n) hs[nbase + n][j] = fmaxf(acc[n], 0.f);
    }
    __syncthreads();

    // ---- layer 2: [D] -> [D], ReLU ----
    {
        float bias = b2[j];
        #pragma unroll
        for (int n = 0; n < NPB / 2; ++n) acc[n] = bias;
        for (int k = 0; k < MODEL_D; k += 4) {
            float w0 = W2[(k + 0) * MODEL_D + j];
            float w1 = W2[(k + 1) * MODEL_D + j];
            float w2 = W2[(k + 2) * MODEL_D + j];
            float w3 = W2[(k + 3) * MODEL_D + j];
            #pragma unroll
            for (int n = 0; n < NPB / 2; ++n) {
                float4 x = *reinterpret_cast<const float4*>(&hs[nbase + n][k]);
                acc[n] = fmaf(x.x, w0, acc[n]);
                acc[n] = fmaf(x.y, w1, acc[n]);
                acc[n] = fmaf(x.z, w2, acc[n]);
                acc[n] = fmaf(x.w, w3, acc[n]);
            }
        }
    }
    __syncthreads();
    #pragma unroll
    for (int n = 0; n < NPB / 2; ++n) xs[nbase + n][j] = fmaxf(acc[n], 0.f);
    __syncthreads();

    // ---- layer 3: [D] -> [D], no activation ----
    {
        float bias = b3[j];
        #pragma unroll
        for (int n = 0; n < NPB / 2; ++n) acc[n] = bias;
        for (int k = 0; k < MODEL_D; k += 4) {
            float w0 = W3[(k + 0) * MODEL_D + j];
            float w1 = W3[(k + 1) * MODEL_D + j];
            float w2 = W3[(k + 2) * MODEL_D + j];
            float w3 = W3[(k + 3) * MODEL_D + j];
            #pragma unroll
            for (int n = 0; n < NPB / 2; ++n) {
                float4 x = *reinterpret_cast<const float4*>(&xs[nbase + n][k]);
                acc[n] = fmaf(x.x, w0, acc[n]);
                acc[n] = fmaf(x.y, w1, acc[n]);
                acc[n] = fmaf(x.z, w2, acc[n]);
                acc[n] = fmaf(x.w, w3, acc[n]);
            }
        }
        #pragma unroll
        for (int n = 0; n < NPB / 2; ++n) {
            int node = n0 + nbase + n;
            if (node < N) out[(size_t)node * MODEL_D + j] = acc[n];
        }
    }
}

extern "C" void kernel_launch(void* const* d_in, const int* in_sizes, int n_in,
                              void* d_out, int out_size, void* d_ws, size_t ws_size,
                              hipStream_t stream) {
    const float* feat = (const float*)d_in[0];
    const int*   src  = (const int*)d_in[1];
    const int*   dst  = (const int*)d_in[2];
    const float* W1   = (const float*)d_in[3];
    const float* b1   = (const float*)d_in[4];
    const float* W2   = (const float*)d_in[5];
    const float* b2   = (const float*)d_in[6];
    const float* W3   = (const float*)d_in[7];
    const float* b3   = (const float*)d_in[8];
    float* out = (float*)d_out;

    const int N = in_sizes[0] / MODEL_D;
    const int E = in_sizes[1];
    const int M = N * K_SUB;

    // ws layout: deg8[8N] | off8[8N] | cursor8[8N] | srcSorted[E] | agg[N*D]
    int* deg8      = (int*)d_ws;
    int* off8      = deg8 + M;
    int* cursor8   = off8 + M;
    int* srcSorted = cursor8 + M;
    float* agg     = (float*)(srcSorted + E);

    hipMemsetAsync(deg8, 0, (size_t)M * sizeof(int), stream);

    int gE = min((E + 1023) / 1024, 1024);
    hist_kernel<<<gE, 1024, 0, stream>>>(dst, deg8, E);
    scan_kernel<<<1, 1024, 0, stream>>>(deg8, off8, cursor8, M);
    fill_kernel<<<gE, 1024, 0, stream>>>(src, dst, cursor8, srcSorted, E);

    int ablocks = (N * MODEL_D + 255) / 256;
    agg_kernel<<<ablocks, 256, 0, stream>>>(feat, off8, deg8, srcSorted, agg, N);

    int mblocks = (N + NPB - 1) / NPB;
    mlp_kernel<<<mblocks, MLP_THREADS, 0, stream>>>(
        agg, feat, W1, b1, W2, b2, W3, b3, out, N);
}

// Round 6
// 141.551 us; speedup vs baseline: 3.5025x; 2.1790x over previous
//
#include <hip/hip_runtime.h>

#define MODEL_D 128
#define NPB 16      // nodes per block in MLP kernel
#define MLP_THREADS 256
#define K_SUB 8     // sub-cursors per node (contention reduction)

// ---------------------------------------------------------------------------
// Step 1: histogram of dst -> deg8[] (8 sub-counters per node, keyed by i&7)
// ---------------------------------------------------------------------------
__global__ __launch_bounds__(1024) void hist_kernel(
    const int* __restrict__ dst, int* __restrict__ deg8, int E)
{
    int i = blockIdx.x * 1024 + threadIdx.x;
    int stride = gridDim.x * 1024;
    for (; i < E; i += stride)
        atomicAdd(&deg8[dst[i] * K_SUB + (i & (K_SUB - 1))], 1);
}

// ---------------------------------------------------------------------------
// Step 2a: per-block (1024-wide tile) reduction of deg8 -> blockSum
// ---------------------------------------------------------------------------
__global__ __launch_bounds__(1024) void scan_pass1(
    const int* __restrict__ deg8, int* __restrict__ blockSum, int M)
{
    __shared__ int wsum[16];
    int t = threadIdx.x;
    int i = blockIdx.x * 1024 + t;
    int v = (i < M) ? deg8[i] : 0;
    #pragma unroll
    for (int d = 32; d > 0; d >>= 1) v += __shfl_down(v, d);
    if ((t & 63) == 0) wsum[t >> 6] = v;
    __syncthreads();
    if (t == 0) {
        int s = 0;
        #pragma unroll
        for (int k = 0; k < 16; ++k) s += wsum[k];
        blockSum[blockIdx.x] = s;
    }
}

// ---------------------------------------------------------------------------
// Step 2b: exclusive scan of blockSum[NB] -> blockBase[NB]  (NB <= 1024)
// ---------------------------------------------------------------------------
__global__ __launch_bounds__(1024) void scan_mid(
    const int* __restrict__ blockSum, int* __restrict__ blockBase, int NB)
{
    __shared__ int sums[1024];
    int t = threadIdx.x;
    sums[t] = (t < NB) ? blockSum[t] : 0;
    __syncthreads();
    for (int d = 1; d < 1024; d <<= 1) {
        int v = (t >= d) ? sums[t - d] : 0;
        __syncthreads();
        sums[t] += v;
        __syncthreads();
    }
    if (t < NB) blockBase[t] = (t == 0) ? 0 : sums[t - 1];
}

// ---------------------------------------------------------------------------
// Step 2c: per-tile exclusive scan + blockBase -> off8, cursor8 (coalesced)
// ---------------------------------------------------------------------------
__global__ __launch_bounds__(1024) void scan_pass2(
    const int* __restrict__ deg8, const int* __restrict__ blockBase,
    int* __restrict__ off8, int* __restrict__ cursor8, int M)
{
    __shared__ int waveSums[16];
    int t = threadIdx.x;
    int i = blockIdx.x * 1024 + t;
    int v = (i < M) ? deg8[i] : 0;
    int lane = t & 63, w = t >> 6;

    // wave-inclusive scan
    int x = v;
    #pragma unroll
    for (int d = 1; d < 64; d <<= 1) {
        int u = __shfl_up(x, d);
        if (lane >= d) x += u;
    }
    if (lane == 63) waveSums[w] = x;
    __syncthreads();
    if (t < 16) {
        int s = waveSums[t];
        #pragma unroll
        for (int d = 1; d < 16; d <<= 1) {
            int u = __shfl_up(s, d);
            if (t >= d) s += u;
        }
        waveSums[t] = s;  // inclusive over wave sums
    }
    __syncthreads();
    int waveBase = (w == 0) ? 0 : waveSums[w - 1];
    int excl = x - v + waveBase + blockBase[blockIdx.x];
    if (i < M) {
        off8[i] = excl;
        cursor8[i] = excl;
    }
}

// ---------------------------------------------------------------------------
// Step 3: bucket fill -> srcSorted[] grouped by dst (8-way sub-cursors)
// ---------------------------------------------------------------------------
__global__ __launch_bounds__(1024) void fill_kernel(
    const int* __restrict__ src, const int* __restrict__ dst,
    int* __restrict__ cursor8, int* __restrict__ srcSorted, int E)
{
    int i = blockIdx.x * 1024 + threadIdx.x;
    int stride = gridDim.x * 1024;
    for (; i < E; i += stride) {
        int pos = atomicAdd(&cursor8[dst[i] * K_SUB + (i & (K_SUB - 1))], 1);
        srcSorted[pos] = src[i];
    }
}

// ---------------------------------------------------------------------------
// Step 4: CSR aggregation, one thread per (node, column). Node's edges are
// the contiguous union of its 8 sublists: [off8[n*8], off8[n*8+7]+deg8[n*8+7]).
// ---------------------------------------------------------------------------
__global__ __launch_bounds__(256) void agg_kernel(
    const float* __restrict__ feat,
    const int* __restrict__ off8, const int* __restrict__ deg8,
    const int* __restrict__ srcSorted,
    float* __restrict__ agg, int N)
{
    int gid = blockIdx.x * 256 + threadIdx.x;
    int node = gid >> 7;
    if (node >= N) return;
    int j = gid & (MODEL_D - 1);

    int base8 = node * K_SUB;
    int beg = off8[base8];
    int cnt = off8[base8 + K_SUB - 1] + deg8[base8 + K_SUB - 1] - beg;

    float a = 0.f;
    int i = 0;
    for (; i + 8 <= cnt; i += 8) {
        int s0 = srcSorted[beg + i + 0];
        int s1 = srcSorted[beg + i + 1];
        int s2 = srcSorted[beg + i + 2];
        int s3 = srcSorted[beg + i + 3];
        int s4 = srcSorted[beg + i + 4];
        int s5 = srcSorted[beg + i + 5];
        int s6 = srcSorted[beg + i + 6];
        int s7 = srcSorted[beg + i + 7];
        float f0 = feat[(size_t)s0 * MODEL_D + j];
        float f1 = feat[(size_t)s1 * MODEL_D + j];
        float f2 = feat[(size_t)s2 * MODEL_D + j];
        float f3 = feat[(size_t)s3 * MODEL_D + j];
        float f4 = feat[(size_t)s4 * MODEL_D + j];
        float f5 = feat[(size_t)s5 * MODEL_D + j];
        float f6 = feat[(size_t)s6 * MODEL_D + j];
        float f7 = feat[(size_t)s7 * MODEL_D + j];
        a += ((f0 + f1) + (f2 + f3)) + ((f4 + f5) + (f6 + f7));
    }
    for (; i < cnt; ++i)
        a += feat[(size_t)srcSorted[beg + i] * MODEL_D + j];
    agg[(size_t)node * MODEL_D + j] = a;
}

// ---------------------------------------------------------------------------
// Step 5: 3-layer MLP. 256 threads/block, 16 nodes/block (625 blocks).
// ---------------------------------------------------------------------------
__global__ __launch_bounds__(MLP_THREADS) void mlp_kernel(
    const float* __restrict__ agg,
    const float* __restrict__ feat,
    const float* __restrict__ W1, const float* __restrict__ b1,
    const float* __restrict__ W2, const float* __restrict__ b2,
    const float* __restrict__ W3, const float* __restrict__ b3,
    float* __restrict__ out,
    int N)
{
    __shared__ float xs[NPB][2 * MODEL_D];  // 16 KB
    __shared__ float hs[NPB][MODEL_D];      // 8 KB

    const int t = threadIdx.x;
    const int j = t & (MODEL_D - 1);
    const int g = t >> 7;          // 0..1
    const int n0 = blockIdx.x * NPB;

    #pragma unroll
    for (int u = 0; u < NPB / 2; ++u) {
        int n = g * (NPB / 2) + u;
        int node = n0 + n;
        float a = 0.f, f = 0.f;
        if (node < N) {
            a = agg[(size_t)node * MODEL_D + j];
            f = feat[(size_t)node * MODEL_D + j];
        }
        xs[n][j] = a;
        xs[n][MODEL_D + j] = f;
    }
    __syncthreads();

    const int nbase = g * (NPB / 2);
    float acc[NPB / 2];

    // ---- layer 1: [2D] -> [D], ReLU ----
    {
        float bias = b1[j];
        #pragma unroll
        for (int n = 0; n < NPB / 2; ++n) acc[n] = bias;
        for (int k = 0; k < 2 * MODEL_D; k += 4) {
            float w0 = W1[(k + 0) * MODEL_D + j];
            float w1 = W1[(k + 1) * MODEL_D + j];
            float w2 = W1[(k + 2) * MODEL_D + j];
            float w3 = W1[(k + 3) * MODEL_D + j];
            #pragma unroll
            for (int n = 0; n < NPB / 2; ++n) {
                float4 x = *reinterpret_cast<const float4*>(&xs[nbase + n][k]);
                acc[n] = fmaf(x.x, w0, acc[n]);
                acc[n] = fmaf(x.y, w1, acc[n]);
                acc[n] = fmaf(x.z, w2, acc[n]);
                acc[n] = fmaf(x.w, w3, acc[n]);
            }
        }
        #pragma unroll
        for (int n = 0; n < NPB / 2; ++n) hs[nbase + n][j] = fmaxf(acc[n], 0.f);
    }
    __syncthreads();

    // ---- layer 2: [D] -> [D], ReLU ----
    {
        float bias = b2[j];
        #pragma unroll
        for (int n = 0; n < NPB / 2; ++n) acc[n] = bias;
        for (int k = 0; k < MODEL_D; k += 4) {
            float w0 = W2[(k + 0) * MODEL_D + j];
            float w1 = W2[(k + 1) * MODEL_D + j];
            float w2 = W2[(k + 2) * MODEL_D + j];
            float w3 = W2[(k + 3) * MODEL_D + j];
            #pragma unroll
            for (int n = 0; n < NPB / 2; ++n) {
                float4 x = *reinterpret_cast<const float4*>(&hs[nbase + n][k]);
                acc[n] = fmaf(x.x, w0, acc[n]);
                acc[n] = fmaf(x.y, w1, acc[n]);
                acc[n] = fmaf(x.z, w2, acc[n]);
                acc[n] = fmaf(x.w, w3, acc[n]);
            }
        }
    }
    __syncthreads();
    #pragma unroll
    for (int n = 0; n < NPB / 2; ++n) xs[nbase + n][j] = fmaxf(acc[n], 0.f);
    __syncthreads();

    // ---- layer 3: [D] -> [D], no activation ----
    {
        float bias = b3[j];
        #pragma unroll
        for (int n = 0; n < NPB / 2; ++n) acc[n] = bias;
        for (int k = 0; k < MODEL_D; k += 4) {
            float w0 = W3[(k + 0) * MODEL_D + j];
            float w1 = W3[(k + 1) * MODEL_D + j];
            float w2 = W3[(k + 2) * MODEL_D + j];
            float w3 = W3[(k + 3) * MODEL_D + j];
            #pragma unroll
            for (int n = 0; n < NPB / 2; ++n) {
                float4 x = *reinterpret_cast<const float4*>(&xs[nbase + n][k]);
                acc[n] = fmaf(x.x, w0, acc[n]);
                acc[n] = fmaf(x.y, w1, acc[n]);
                acc[n] = fmaf(x.z, w2, acc[n]);
                acc[n] = fmaf(x.w, w3, acc[n]);
            }
        }
        #pragma unroll
        for (int n = 0; n < NPB / 2; ++n) {
            int node = n0 + nbase + n;
            if (node < N) out[(size_t)node * MODEL_D + j] = acc[n];
        }
    }
}

extern "C" void kernel_launch(void* const* d_in, const int* in_sizes, int n_in,
                              void* d_out, int out_size, void* d_ws, size_t ws_size,
                              hipStream_t stream) {
    const float* feat = (const float*)d_in[0];
    const int*   src  = (const int*)d_in[1];
    const int*   dst  = (const int*)d_in[2];
    const float* W1   = (const float*)d_in[3];
    const float* b1   = (const float*)d_in[4];
    const float* W2   = (const float*)d_in[5];
    const float* b2   = (const float*)d_in[6];
    const float* W3   = (const float*)d_in[7];
    const float* b3   = (const float*)d_in[8];
    float* out = (float*)d_out;

    const int N = in_sizes[0] / MODEL_D;
    const int E = in_sizes[1];
    const int M = N * K_SUB;
    const int NB = (M + 1023) / 1024;  // scan tiles (must be <= 1024)

    // ws layout: deg8[M] | off8[M] | cursor8[M] | blockSum[NB] | blockBase[NB]
    //            | srcSorted[E] | agg[N*D]
    int* deg8      = (int*)d_ws;
    int* off8      = deg8 + M;
    int* cursor8   = off8 + M;
    int* blockSum  = cursor8 + M;
    int* blockBase = blockSum + NB;
    int* srcSorted = blockBase + NB;
    float* agg     = (float*)(srcSorted + E);

    hipMemsetAsync(deg8, 0, (size_t)M * sizeof(int), stream);

    int gE = min((E + 1023) / 1024, 1024);
    hist_kernel<<<gE, 1024, 0, stream>>>(dst, deg8, E);
    scan_pass1<<<NB, 1024, 0, stream>>>(deg8, blockSum, M);
    scan_mid<<<1, 1024, 0, stream>>>(blockSum, blockBase, NB);
    scan_pass2<<<NB, 1024, 0, stream>>>(deg8, blockBase, off8, cursor8, M);
    fill_kernel<<<gE, 1024, 0, stream>>>(src, dst, cursor8, srcSorted, E);

    int ablocks = (N * MODEL_D + 255) / 256;
    agg_kernel<<<ablocks, 256, 0, stream>>>(feat, off8, deg8, srcSorted, agg, N);

    int mblocks = (N + NPB - 1) / NPB;
    mlp_kernel<<<mblocks, MLP_THREADS, 0, stream>>>(
        agg, feat, W1, b1, W2, b2, W3, b3, out, N);
}

// Round 7
// 116.209 us; speedup vs baseline: 4.2662x; 1.2181x over previous
//
#include <hip/hip_runtime.h>
#include <hip/hip_bf16.h>

#define MODEL_D 128
#define K_SUB 8     // sub-cursors per node (contention reduction)

typedef unsigned short ushort_t;
typedef __attribute__((ext_vector_type(8))) short short8v;  // 8 bf16 (4 VGPRs)
typedef __attribute__((ext_vector_type(4))) float f32x4;

static __device__ __forceinline__ ushort_t f2b(float v) {
    __hip_bfloat16 h = __float2bfloat16(v);  // RNE
    return *reinterpret_cast<ushort_t*>(&h);
}

// ---------------------------------------------------------------------------
// Convert feat -> bf16 featB; W1,W2,W3 -> bf16 TRANSPOSED (Wt[j][k] = W[k][j])
// so MFMA B-fragments are contiguous-16B loads.
// ---------------------------------------------------------------------------
__global__ __launch_bounds__(256) void convert_kernel(
    const float* __restrict__ feat,
    const float* __restrict__ W1, const float* __restrict__ W2,
    const float* __restrict__ W3,
    ushort_t* __restrict__ featB, ushort_t* __restrict__ W1t,
    ushort_t* __restrict__ W2t, ushort_t* __restrict__ W3t,
    int nFeat)
{
    const int n1 = 256 * 128, n2 = 128 * 128, n3 = 128 * 128;
    int total = nFeat + n1 + n2 + n3;
    int i = blockIdx.x * 256 + threadIdx.x;
    int stride = gridDim.x * 256;
    for (; i < total; i += stride) {
        if (i < nFeat) {
            featB[i] = f2b(feat[i]);
        } else if (i < nFeat + n1) {
            int idx = i - nFeat; int j = idx >> 8, k = idx & 255;
            W1t[idx] = f2b(W1[k * 128 + j]);
        } else if (i < nFeat + n1 + n2) {
            int idx = i - nFeat - n1; int j = idx >> 7, k = idx & 127;
            W2t[idx] = f2b(W2[k * 128 + j]);
        } else {
            int idx = i - nFeat - n1 - n2; int j = idx >> 7, k = idx & 127;
            W3t[idx] = f2b(W3[k * 128 + j]);
        }
    }
}

// ---------------------------------------------------------------------------
// CSR build (unchanged from round 6): hist -> 3-kernel scan -> fill
// ---------------------------------------------------------------------------
__global__ __launch_bounds__(1024) void hist_kernel(
    const int* __restrict__ dst, int* __restrict__ deg8, int E)
{
    int i = blockIdx.x * 1024 + threadIdx.x;
    int stride = gridDim.x * 1024;
    for (; i < E; i += stride)
        atomicAdd(&deg8[dst[i] * K_SUB + (i & (K_SUB - 1))], 1);
}

__global__ __launch_bounds__(1024) void scan_pass1(
    const int* __restrict__ deg8, int* __restrict__ blockSum, int M)
{
    __shared__ int wsum[16];
    int t = threadIdx.x;
    int i = blockIdx.x * 1024 + t;
    int v = (i < M) ? deg8[i] : 0;
    #pragma unroll
    for (int d = 32; d > 0; d >>= 1) v += __shfl_down(v, d);
    if ((t & 63) == 0) wsum[t >> 6] = v;
    __syncthreads();
    if (t == 0) {
        int s = 0;
        #pragma unroll
        for (int k = 0; k < 16; ++k) s += wsum[k];
        blockSum[blockIdx.x] = s;
    }
}

__global__ __launch_bounds__(1024) void scan_mid(
    const int* __restrict__ blockSum, int* __restrict__ blockBase, int NB)
{
    __shared__ int sums[1024];
    int t = threadIdx.x;
    sums[t] = (t < NB) ? blockSum[t] : 0;
    __syncthreads();
    for (int d = 1; d < 1024; d <<= 1) {
        int v = (t >= d) ? sums[t - d] : 0;
        __syncthreads();
        sums[t] += v;
        __syncthreads();
    }
    if (t < NB) blockBase[t] = (t == 0) ? 0 : sums[t - 1];
}

__global__ __launch_bounds__(1024) void scan_pass2(
    const int* __restrict__ deg8, const int* __restrict__ blockBase,
    int* __restrict__ off8, int* __restrict__ cursor8, int M)
{
    __shared__ int waveSums[16];
    int t = threadIdx.x;
    int i = blockIdx.x * 1024 + t;
    int v = (i < M) ? deg8[i] : 0;
    int lane = t & 63, w = t >> 6;
    int x = v;
    #pragma unroll
    for (int d = 1; d < 64; d <<= 1) {
        int u = __shfl_up(x, d);
        if (lane >= d) x += u;
    }
    if (lane == 63) waveSums[w] = x;
    __syncthreads();
    if (t < 16) {
        int s = waveSums[t];
        #pragma unroll
        for (int d = 1; d < 16; d <<= 1) {
            int u = __shfl_up(s, d);
            if (t >= d) s += u;
        }
        waveSums[t] = s;
    }
    __syncthreads();
    int waveBase = (w == 0) ? 0 : waveSums[w - 1];
    int excl = x - v + waveBase + blockBase[blockIdx.x];
    if (i < M) {
        off8[i] = excl;
        cursor8[i] = excl;
    }
}

__global__ __launch_bounds__(1024) void fill_kernel(
    const int* __restrict__ src, const int* __restrict__ dst,
    int* __restrict__ cursor8, int* __restrict__ srcSorted, int E)
{
    int i = blockIdx.x * 1024 + threadIdx.x;
    int stride = gridDim.x * 1024;
    for (; i < E; i += stride) {
        int pos = atomicAdd(&cursor8[dst[i] * K_SUB + (i & (K_SUB - 1))], 1);
        srcSorted[pos] = src[i];
    }
}

// ---------------------------------------------------------------------------
// CSR aggregation over bf16 feat. One WAVE per node; lane owns 2 columns
// (uint load = 2 bf16), fp32 accumulation, bf16 output.
// After fill, cursor8[i] == end of sublist i, so node range =
// [off8[n*8], cursor8[n*8+7]).  featB is 2.56 MB -> L2-resident gathers.
// ---------------------------------------------------------------------------
__global__ __launch_bounds__(256) void agg_kernel(
    const ushort_t* __restrict__ featB,
    const int* __restrict__ off8, const int* __restrict__ endc,
    const int* __restrict__ srcSorted,
    ushort_t* __restrict__ aggB, int N)
{
    int gid = blockIdx.x * 256 + threadIdx.x;
    int node = gid >> 6;
    if (node >= N) return;
    int lane2 = (gid & 63) << 1;   // column pair

    int beg = off8[node * K_SUB];
    int end = endc[node * K_SUB + K_SUB - 1];

    float a0 = 0.f, a1 = 0.f;
    int i = beg;
    for (; i + 8 <= end; i += 8) {
        #pragma unroll
        for (int u = 0; u < 8; ++u) {
            int s = srcSorted[i + u];
            unsigned int w = *(const unsigned int*)(featB + (size_t)s * MODEL_D + lane2);
            union { unsigned int u32; float f; } lo, hi;
            lo.u32 = w << 16;
            hi.u32 = w & 0xffff0000u;
            a0 += lo.f;
            a1 += hi.f;
        }
    }
    for (; i < end; ++i) {
        int s = srcSorted[i];
        unsigned int w = *(const unsigned int*)(featB + (size_t)s * MODEL_D + lane2);
        union { unsigned int u32; float f; } lo, hi;
        lo.u32 = w << 16;
        hi.u32 = w & 0xffff0000u;
        a0 += lo.f;
        a1 += hi.f;
    }
    unsigned int o = (unsigned int)f2b(a0) | ((unsigned int)f2b(a1) << 16);
    *(unsigned int*)(aggB + (size_t)node * MODEL_D + lane2) = o;
}

// ---------------------------------------------------------------------------
// MFMA MLP: 16 nodes/block, 256 threads (4 waves), wave w does column tiles
// {2w, 2w+1}. A rows = lane&15 (node blk0+r16); k-groups g=lane>>4 hold 8
// consecutive k (same bijection for A and B frags -> permutation cancels).
// C/D: col=lane&15, row=(lane>>4)*4+reg [m89-verified]. h1/h2 in LDS as
// bf16, rows padded to 136 ushorts (272 B) to avoid ds_read_b128 bank
// conflicts at 256 B stride.
// ---------------------------------------------------------------------------
__global__ __launch_bounds__(256) void mlp_mfma_kernel(
    const ushort_t* __restrict__ aggB, const ushort_t* __restrict__ featB,
    const ushort_t* __restrict__ W1t, const ushort_t* __restrict__ W2t,
    const ushort_t* __restrict__ W3t,
    const float* __restrict__ b1, const float* __restrict__ b2,
    const float* __restrict__ b3,
    float* __restrict__ out, int N)
{
    __shared__ ushort_t h1[16][136];
    __shared__ ushort_t h2[16][136];

    const int t = threadIdx.x;
    const int lane = t & 63;
    const int wid = t >> 6;          // 0..3
    const int r16 = lane & 15;
    const int g = lane >> 4;         // 0..3
    const int blk0 = blockIdx.x * 16;

    const int nodeA = blk0 + r16;
    const int nodeAc = (nodeA < N) ? nodeA : (N - 1);

    // ---- A-fragments for layer 1: x = [aggB | featB], k = ks*32 + g*8 + e
    short8v a1f[8];
    #pragma unroll
    for (int ks = 0; ks < 4; ++ks)
        a1f[ks] = *(const short8v*)(aggB + (size_t)nodeAc * MODEL_D + ks * 32 + g * 8);
    #pragma unroll
    for (int ks = 0; ks < 4; ++ks)
        a1f[4 + ks] = *(const short8v*)(featB + (size_t)nodeAc * MODEL_D + ks * 32 + g * 8);

    // ---- layer 1: [256] -> [128], ReLU ----
    #pragma unroll
    for (int cc = 0; cc < 2; ++cc) {
        const int ct = wid * 2 + cc;
        f32x4 c = {0.f, 0.f, 0.f, 0.f};
        #pragma unroll
        for (int ks = 0; ks < 8; ++ks) {
            short8v b = *(const short8v*)(W1t + (ct * 16 + r16) * 256 + ks * 32 + g * 8);
            c = __builtin_amdgcn_mfma_f32_16x16x32_bf16(a1f[ks], b, c, 0, 0, 0);
        }
        const float bias = b1[ct * 16 + r16];
        #pragma unroll
        for (int i = 0; i < 4; ++i) {
            float v = fmaxf(c[i] + bias, 0.f);
            h1[g * 4 + i][ct * 16 + r16] = f2b(v);
        }
    }
    __syncthreads();

    // ---- layer 2: [128] -> [128], ReLU ----
    short8v a2f[4];
    #pragma unroll
    for (int ks = 0; ks < 4; ++ks)
        a2f[ks] = *(const short8v*)&h1[r16][ks * 32 + g * 8];
    #pragma unroll
    for (int cc = 0; cc < 2; ++cc) {
        const int ct = wid * 2 + cc;
        f32x4 c = {0.f, 0.f, 0.f, 0.f};
        #pragma unroll
        for (int ks = 0; ks < 4; ++ks) {
            short8v b = *(const short8v*)(W2t + (ct * 16 + r16) * 128 + ks * 32 + g * 8);
            c = __builtin_amdgcn_mfma_f32_16x16x32_bf16(a2f[ks], b, c, 0, 0, 0);
        }
        const float bias = b2[ct * 16 + r16];
        #pragma unroll
        for (int i = 0; i < 4; ++i) {
            float v = fmaxf(c[i] + bias, 0.f);
            h2[g * 4 + i][ct * 16 + r16] = f2b(v);
        }
    }
    __syncthreads();

    // ---- layer 3: [128] -> [128], fp32 out ----
    short8v a3f[4];
    #pragma unroll
    for (int ks = 0; ks < 4; ++ks)
        a3f[ks] = *(const short8v*)&h2[r16][ks * 32 + g * 8];
    #pragma unroll
    for (int cc = 0; cc < 2; ++cc) {
        const int ct = wid * 2 + cc;
        f32x4 c = {0.f, 0.f, 0.f, 0.f};
        #pragma unroll
        for (int ks = 0; ks < 4; ++ks) {
            short8v b = *(const short8v*)(W3t + (ct * 16 + r16) * 128 + ks * 32 + g * 8);
            c = __builtin_amdgcn_mfma_f32_16x16x32_bf16(a3f[ks], b, c, 0, 0, 0);
        }
        const float bias = b3[ct * 16 + r16];
        #pragma unroll
        for (int i = 0; i < 4; ++i) {
            int node = blk0 + g * 4 + i;
            if (node < N)
                out[(size_t)node * MODEL_D + ct * 16 + r16] = c[i] + bias;
        }
    }
}

extern "C" void kernel_launch(void* const* d_in, const int* in_sizes, int n_in,
                              void* d_out, int out_size, void* d_ws, size_t ws_size,
                              hipStream_t stream) {
    const float* feat = (const float*)d_in[0];
    const int*   src  = (const int*)d_in[1];
    const int*   dst  = (const int*)d_in[2];
    const float* W1   = (const float*)d_in[3];
    const float* b1   = (const float*)d_in[4];
    const float* W2   = (const float*)d_in[5];
    const float* b2   = (const float*)d_in[6];
    const float* W3   = (const float*)d_in[7];
    const float* b3   = (const float*)d_in[8];
    float* out = (float*)d_out;

    const int N = in_sizes[0] / MODEL_D;
    const int E = in_sizes[1];
    const int NFEAT = N * MODEL_D;
    const int M = N * K_SUB;
    const int NB = (M + 1023) / 1024;

    // ws layout: bf16 buffers first (16B aligned), then int CSR arrays
    ushort_t* featB = (ushort_t*)d_ws;
    ushort_t* aggB  = featB + NFEAT;
    ushort_t* W1t   = aggB + NFEAT;
    ushort_t* W2t   = W1t + 256 * 128;
    ushort_t* W3t   = W2t + 128 * 128;
    int* deg8       = (int*)(W3t + 128 * 128);
    int* off8       = deg8 + M;
    int* cursor8    = off8 + M;
    int* blockSum   = cursor8 + M;
    int* blockBase  = blockSum + NB;
    int* srcSorted  = blockBase + NB;

    hipMemsetAsync(deg8, 0, (size_t)M * sizeof(int), stream);

    int cvtTotal = NFEAT + 256 * 128 + 128 * 128 + 128 * 128;
    convert_kernel<<<(cvtTotal + 255) / 256, 256, 0, stream>>>(
        feat, W1, W2, W3, featB, W1t, W2t, W3t, NFEAT);

    int gE = min((E + 1023) / 1024, 1024);
    hist_kernel<<<gE, 1024, 0, stream>>>(dst, deg8, E);
    scan_pass1<<<NB, 1024, 0, stream>>>(deg8, blockSum, M);
    scan_mid<<<1, 1024, 0, stream>>>(blockSum, blockBase, NB);
    scan_pass2<<<NB, 1024, 0, stream>>>(deg8, blockBase, off8, cursor8, M);
    fill_kernel<<<gE, 1024, 0, stream>>>(src, dst, cursor8, srcSorted, E);

    // after fill, cursor8[i] == end of sublist i
    int ablocks = (N * 64 + 255) / 256;   // one wave per node
    agg_kernel<<<ablocks, 256, 0, stream>>>(featB, off8, cursor8, srcSorted, aggB, N);

    int mblocks = (N + 15) / 16;
    mlp_mfma_kernel<<<mblocks, 256, 0, stream>>>(
        aggB, featB, W1t, W2t, W3t, b1, b2, b3, out, N);
}

// Round 8
// 115.437 us; speedup vs baseline: 4.2948x; 1.0067x over previous
//
#include <hip/hip_runtime.h>
#include <hip/hip_bf16.h>

#define MODEL_D 128
#define K_SUB 8     // sub-cursors per node (contention reduction)

typedef unsigned short ushort_t;
typedef __attribute__((ext_vector_type(8))) short short8v;  // 8 bf16 (4 VGPRs)
typedef __attribute__((ext_vector_type(4))) float f32x4;

static __device__ __forceinline__ ushort_t f2b(float v) {
    __hip_bfloat16 h = __float2bfloat16(v);  // RNE
    return *reinterpret_cast<ushort_t*>(&h);
}

// ---------------------------------------------------------------------------
// Zero deg8 (replaces hipMemsetAsync: rocclr fillBuffer ran ~41 us with a
// tiny grid; this is a full-grid coalesced store, ~2 us)
// ---------------------------------------------------------------------------
__global__ __launch_bounds__(1024) void zero_kernel(int* __restrict__ p, int M)
{
    int i = blockIdx.x * 1024 + threadIdx.x;
    if (i < M) p[i] = 0;
}

// ---------------------------------------------------------------------------
// Convert feat -> bf16 featB; W1,W2,W3 -> bf16 TRANSPOSED (Wt[j][k] = W[k][j])
// so MFMA B-fragments are contiguous-16B loads.
// ---------------------------------------------------------------------------
__global__ __launch_bounds__(256) void convert_kernel(
    const float* __restrict__ feat,
    const float* __restrict__ W1, const float* __restrict__ W2,
    const float* __restrict__ W3,
    ushort_t* __restrict__ featB, ushort_t* __restrict__ W1t,
    ushort_t* __restrict__ W2t, ushort_t* __restrict__ W3t,
    int nFeat)
{
    const int n1 = 256 * 128, n2 = 128 * 128, n3 = 128 * 128;
    int total = nFeat + n1 + n2 + n3;
    int i = blockIdx.x * 256 + threadIdx.x;
    int stride = gridDim.x * 256;
    for (; i < total; i += stride) {
        if (i < nFeat) {
            featB[i] = f2b(feat[i]);
        } else if (i < nFeat + n1) {
            int idx = i - nFeat; int j = idx >> 8, k = idx & 255;
            W1t[idx] = f2b(W1[k * 128 + j]);
        } else if (i < nFeat + n1 + n2) {
            int idx = i - nFeat - n1; int j = idx >> 7, k = idx & 127;
            W2t[idx] = f2b(W2[k * 128 + j]);
        } else {
            int idx = i - nFeat - n1 - n2; int j = idx >> 7, k = idx & 127;
            W3t[idx] = f2b(W3[k * 128 + j]);
        }
    }
}

// ---------------------------------------------------------------------------
// CSR build: hist -> 3-kernel scan -> fill
// ---------------------------------------------------------------------------
__global__ __launch_bounds__(1024) void hist_kernel(
    const int* __restrict__ dst, int* __restrict__ deg8, int E)
{
    int i = blockIdx.x * 1024 + threadIdx.x;
    int stride = gridDim.x * 1024;
    for (; i < E; i += stride)
        atomicAdd(&deg8[dst[i] * K_SUB + (i & (K_SUB - 1))], 1);
}

__global__ __launch_bounds__(1024) void scan_pass1(
    const int* __restrict__ deg8, int* __restrict__ blockSum, int M)
{
    __shared__ int wsum[16];
    int t = threadIdx.x;
    int i = blockIdx.x * 1024 + t;
    int v = (i < M) ? deg8[i] : 0;
    #pragma unroll
    for (int d = 32; d > 0; d >>= 1) v += __shfl_down(v, d);
    if ((t & 63) == 0) wsum[t >> 6] = v;
    __syncthreads();
    if (t == 0) {
        int s = 0;
        #pragma unroll
        for (int k = 0; k < 16; ++k) s += wsum[k];
        blockSum[blockIdx.x] = s;
    }
}

__global__ __launch_bounds__(1024) void scan_mid(
    const int* __restrict__ blockSum, int* __restrict__ blockBase, int NB)
{
    __shared__ int sums[1024];
    int t = threadIdx.x;
    sums[t] = (t < NB) ? blockSum[t] : 0;
    __syncthreads();
    for (int d = 1; d < 1024; d <<= 1) {
        int v = (t >= d) ? sums[t - d] : 0;
        __syncthreads();
        sums[t] += v;
        __syncthreads();
    }
    if (t < NB) blockBase[t] = (t == 0) ? 0 : sums[t - 1];
}

__global__ __launch_bounds__(1024) void scan_pass2(
    const int* __restrict__ deg8, const int* __restrict__ blockBase,
    int* __restrict__ off8, int* __restrict__ cursor8, int M)
{
    __shared__ int waveSums[16];
    int t = threadIdx.x;
    int i = blockIdx.x * 1024 + t;
    int v = (i < M) ? deg8[i] : 0;
    int lane = t & 63, w = t >> 6;
    int x = v;
    #pragma unroll
    for (int d = 1; d < 64; d <<= 1) {
        int u = __shfl_up(x, d);
        if (lane >= d) x += u;
    }
    if (lane == 63) waveSums[w] = x;
    __syncthreads();
    if (t < 16) {
        int s = waveSums[t];
        #pragma unroll
        for (int d = 1; d < 16; d <<= 1) {
            int u = __shfl_up(s, d);
            if (t >= d) s += u;
        }
        waveSums[t] = s;
    }
    __syncthreads();
    int waveBase = (w == 0) ? 0 : waveSums[w - 1];
    int excl = x - v + waveBase + blockBase[blockIdx.x];
    if (i < M) {
        off8[i] = excl;
        cursor8[i] = excl;
    }
}

__global__ __launch_bounds__(1024) void fill_kernel(
    const int* __restrict__ src, const int* __restrict__ dst,
    int* __restrict__ cursor8, int* __restrict__ srcSorted, int E)
{
    int i = blockIdx.x * 1024 + threadIdx.x;
    int stride = gridDim.x * 1024;
    for (; i < E; i += stride) {
        int pos = atomicAdd(&cursor8[dst[i] * K_SUB + (i & (K_SUB - 1))], 1);
        srcSorted[pos] = src[i];
    }
}

// ---------------------------------------------------------------------------
// CSR aggregation over bf16 feat. One WAVE per node; lane owns 2 columns
// (uint load = 2 bf16), fp32 accumulation, bf16 output.
// After fill, cursor8[i] == end of sublist i, so node range =
// [off8[n*8], cursor8[n*8+7]).  featB is 2.56 MB -> L2-resident gathers.
// ---------------------------------------------------------------------------
__global__ __launch_bounds__(256) void agg_kernel(
    const ushort_t* __restrict__ featB,
    const int* __restrict__ off8, const int* __restrict__ endc,
    const int* __restrict__ srcSorted,
    ushort_t* __restrict__ aggB, int N)
{
    int gid = blockIdx.x * 256 + threadIdx.x;
    int node = gid >> 6;
    if (node >= N) return;
    int lane2 = (gid & 63) << 1;   // column pair

    int beg = off8[node * K_SUB];
    int end = endc[node * K_SUB + K_SUB - 1];

    float a0 = 0.f, a1 = 0.f;
    int i = beg;
    for (; i + 8 <= end; i += 8) {
        #pragma unroll
        for (int u = 0; u < 8; ++u) {
            int s = srcSorted[i + u];
            unsigned int w = *(const unsigned int*)(featB + (size_t)s * MODEL_D + lane2);
            union { unsigned int u32; float f; } lo, hi;
            lo.u32 = w << 16;
            hi.u32 = w & 0xffff0000u;
            a0 += lo.f;
            a1 += hi.f;
        }
    }
    for (; i < end; ++i) {
        int s = srcSorted[i];
        unsigned int w = *(const unsigned int*)(featB + (size_t)s * MODEL_D + lane2);
        union { unsigned int u32; float f; } lo, hi;
        lo.u32 = w << 16;
        hi.u32 = w & 0xffff0000u;
        a0 += lo.f;
        a1 += hi.f;
    }
    unsigned int o = (unsigned int)f2b(a0) | ((unsigned int)f2b(a1) << 16);
    *(unsigned int*)(aggB + (size_t)node * MODEL_D + lane2) = o;
}

// ---------------------------------------------------------------------------
// MFMA MLP: 16 nodes/block, 256 threads (4 waves), wave w does column tiles
// {2w, 2w+1}. A rows = lane&15 (node blk0+r16); k-groups g=lane>>4 hold 8
// consecutive k (same bijection for A and B frags -> permutation cancels).
// C/D: col=lane&15, row=(lane>>4)*4+reg [m89-verified]. h1/h2 in LDS as
// bf16, rows padded to 136 ushorts (272 B) to avoid ds_read_b128 bank
// conflicts at 256 B stride.
// ---------------------------------------------------------------------------
__global__ __launch_bounds__(256) void mlp_mfma_kernel(
    const ushort_t* __restrict__ aggB, const ushort_t* __restrict__ featB,
    const ushort_t* __restrict__ W1t, const ushort_t* __restrict__ W2t,
    const ushort_t* __restrict__ W3t,
    const float* __restrict__ b1, const float* __restrict__ b2,
    const float* __restrict__ b3,
    float* __restrict__ out, int N)
{
    __shared__ ushort_t h1[16][136];
    __shared__ ushort_t h2[16][136];

    const int t = threadIdx.x;
    const int lane = t & 63;
    const int wid = t >> 6;          // 0..3
    const int r16 = lane & 15;
    const int g = lane >> 4;         // 0..3
    const int blk0 = blockIdx.x * 16;

    const int nodeA = blk0 + r16;
    const int nodeAc = (nodeA < N) ? nodeA : (N - 1);

    // ---- A-fragments for layer 1: x = [aggB | featB], k = ks*32 + g*8 + e
    short8v a1f[8];
    #pragma unroll
    for (int ks = 0; ks < 4; ++ks)
        a1f[ks] = *(const short8v*)(aggB + (size_t)nodeAc * MODEL_D + ks * 32 + g * 8);
    #pragma unroll
    for (int ks = 0; ks < 4; ++ks)
        a1f[4 + ks] = *(const short8v*)(featB + (size_t)nodeAc * MODEL_D + ks * 32 + g * 8);

    // ---- layer 1: [256] -> [128], ReLU ----
    #pragma unroll
    for (int cc = 0; cc < 2; ++cc) {
        const int ct = wid * 2 + cc;
        f32x4 c = {0.f, 0.f, 0.f, 0.f};
        #pragma unroll
        for (int ks = 0; ks < 8; ++ks) {
            short8v b = *(const short8v*)(W1t + (ct * 16 + r16) * 256 + ks * 32 + g * 8);
            c = __builtin_amdgcn_mfma_f32_16x16x32_bf16(a1f[ks], b, c, 0, 0, 0);
        }
        const float bias = b1[ct * 16 + r16];
        #pragma unroll
        for (int i = 0; i < 4; ++i) {
            float v = fmaxf(c[i] + bias, 0.f);
            h1[g * 4 + i][ct * 16 + r16] = f2b(v);
        }
    }
    __syncthreads();

    // ---- layer 2: [128] -> [128], ReLU ----
    short8v a2f[4];
    #pragma unroll
    for (int ks = 0; ks < 4; ++ks)
        a2f[ks] = *(const short8v*)&h1[r16][ks * 32 + g * 8];
    #pragma unroll
    for (int cc = 0; cc < 2; ++cc) {
        const int ct = wid * 2 + cc;
        f32x4 c = {0.f, 0.f, 0.f, 0.f};
        #pragma unroll
        for (int ks = 0; ks < 4; ++ks) {
            short8v b = *(const short8v*)(W2t + (ct * 16 + r16) * 128 + ks * 32 + g * 8);
            c = __builtin_amdgcn_mfma_f32_16x16x32_bf16(a2f[ks], b, c, 0, 0, 0);
        }
        const float bias = b2[ct * 16 + r16];
        #pragma unroll
        for (int i = 0; i < 4; ++i) {
            float v = fmaxf(c[i] + bias, 0.f);
            h2[g * 4 + i][ct * 16 + r16] = f2b(v);
        }
    }
    __syncthreads();

    // ---- layer 3: [128] -> [128], fp32 out ----
    short8v a3f[4];
    #pragma unroll
    for (int ks = 0; ks < 4; ++ks)
        a3f[ks] = *(const short8v*)&h2[r16][ks * 32 + g * 8];
    #pragma unroll
    for (int cc = 0; cc < 2; ++cc) {
        const int ct = wid * 2 + cc;
        f32x4 c = {0.f, 0.f, 0.f, 0.f};
        #pragma unroll
        for (int ks = 0; ks < 4; ++ks) {
            short8v b = *(const short8v*)(W3t + (ct * 16 + r16) * 128 + ks * 32 + g * 8);
            c = __builtin_amdgcn_mfma_f32_16x16x32_bf16(a3f[ks], b, c, 0, 0, 0);
        }
        const float bias = b3[ct * 16 + r16];
        #pragma unroll
        for (int i = 0; i < 4; ++i) {
            int node = blk0 + g * 4 + i;
            if (node < N)
                out[(size_t)node * MODEL_D + ct * 16 + r16] = c[i] + bias;
        }
    }
}

extern "C" void kernel_launch(void* const* d_in, const int* in_sizes, int n_in,
                              void* d_out, int out_size, void* d_ws, size_t ws_size,
                              hipStream_t stream) {
    const float* feat = (const float*)d_in[0];
    const int*   src  = (const int*)d_in[1];
    const int*   dst  = (const int*)d_in[2];
    const float* W1   = (const float*)d_in[3];
    const float* b1   = (const float*)d_in[4];
    const float* W2   = (const float*)d_in[5];
    const float* b2   = (const float*)d_in[6];
    const float* W3   = (const float*)d_in[7];
    const float* b3   = (const float*)d_in[8];
    float* out = (float*)d_out;

    const int N = in_sizes[0] / MODEL_D;
    const int E = in_sizes[1];
    const int NFEAT = N * MODEL_D;
    const int M = N * K_SUB;
    const int NB = (M + 1023) / 1024;

    // ws layout: bf16 buffers first (16B aligned), then int CSR arrays
    ushort_t* featB = (ushort_t*)d_ws;
    ushort_t* aggB  = featB + NFEAT;
    ushort_t* W1t   = aggB + NFEAT;
    ushort_t* W2t   = W1t + 256 * 128;
    ushort_t* W3t   = W2t + 128 * 128;
    int* deg8       = (int*)(W3t + 128 * 128);
    int* off8       = deg8 + M;
    int* cursor8    = off8 + M;
    int* blockSum   = cursor8 + M;
    int* blockBase  = blockSum + NB;
    int* srcSorted  = blockBase + NB;

    zero_kernel<<<NB, 1024, 0, stream>>>(deg8, M);

    int cvtTotal = NFEAT + 256 * 128 + 128 * 128 + 128 * 128;
    convert_kernel<<<(cvtTotal + 255) / 256, 256, 0, stream>>>(
        feat, W1, W2, W3, featB, W1t, W2t, W3t, NFEAT);

    int gE = min((E + 1023) / 1024, 1024);
    hist_kernel<<<gE, 1024, 0, stream>>>(dst, deg8, E);
    scan_pass1<<<NB, 1024, 0, stream>>>(deg8, blockSum, M);
    scan_mid<<<1, 1024, 0, stream>>>(blockSum, blockBase, NB);
    scan_pass2<<<NB, 1024, 0, stream>>>(deg8, blockBase, off8, cursor8, M);
    fill_kernel<<<gE, 1024, 0, stream>>>(src, dst, cursor8, srcSorted, E);

    // after fill, cursor8[i] == end of sublist i
    int ablocks = (N * 64 + 255) / 256;   // one wave per node
    agg_kernel<<<ablocks, 256, 0, stream>>>(featB, off8, cursor8, srcSorted, aggB, N);

    int mblocks = (N + 15) / 16;
    mlp_mfma_kernel<<<mblocks, 256, 0, stream>>>(
        aggB, featB, W1t, W2t, W3t, b1, b2, b3, out, N);
}